// Round 13
// baseline (611.473 us; speedup 1.0000x reference)
//
#include <hip/hip_runtime.h>
#include <stdint.h>

typedef unsigned short u16;
typedef __attribute__((ext_vector_type(8))) short bf16x8;
typedef __attribute__((ext_vector_type(8))) u16 u16x8;
typedef __attribute__((ext_vector_type(4))) u16 u16x4;
typedef __attribute__((ext_vector_type(4))) float f32x4;
typedef __attribute__((ext_vector_type(16))) float f32x16;

#define B_ 16
#define S_ 1024
#define D_ 768
#define H_ 12

__device__ __forceinline__ float bf2f(u16 u) {
  unsigned int x = ((unsigned int)u) << 16;
  float f;
  __builtin_memcpy(&f, &x, 4);
  return f;
}
__device__ __forceinline__ u16 f2bf(float f) {
  unsigned int x;
  __builtin_memcpy(&x, &f, 4);
  x += 0x7fffu + ((x >> 16) & 1u);
  return (u16)(x >> 16);
}

#define MFMA16(a, b, c) __builtin_amdgcn_mfma_f32_16x16x32_bf16((a), (b), (c), 0, 0, 0)
#define MFMA32(a, b, c) __builtin_amdgcn_mfma_f32_32x32x16_bf16((a), (b), (c), 0, 0, 0)

#define GLD16(g, l)                                              \
  __builtin_amdgcn_global_load_lds(                              \
      (const __attribute__((address_space(1))) void*)(g),        \
      (__attribute__((address_space(3))) void*)(l), 16, 0, 0)

// ---------------------------------------------------------------------------
// prep: weight transpose + convert only (x is consumed as f32 by gemmAS<0>).
// ---------------------------------------------------------------------------
__global__ __launch_bounds__(256) void prep(const float* __restrict__ Wqkv,
                                            u16* __restrict__ WqkvT,
                                            const float* __restrict__ Wo,
                                            u16* __restrict__ WoT) {
  __shared__ u16 tt[32][33];
  const int gx = blockIdx.x;
  const int tid = threadIdx.x;
  const int tx = tid & 31, ty = tid >> 5;
  if (gx < 1728) {  // Wqkv [768,2304] -> WqkvT [2304,768]
    const int n0 = (gx % 72) * 32, k0 = (gx / 72) * 32;
#pragma unroll
    for (int i = 0; i < 32; i += 8)
      tt[ty + i][tx] = f2bf(Wqkv[(size_t)(k0 + ty + i) * 2304 + n0 + tx]);
    __syncthreads();
#pragma unroll
    for (int i = 0; i < 32; i += 8)
      WqkvT[(size_t)(n0 + ty + i) * 768 + k0 + tx] = tt[tx][ty + i];
  } else {  // Wo [768,768] -> WoT [768,768]
    const int t = gx - 1728;
    const int n0 = (t % 24) * 32, k0 = (t / 24) * 32;
#pragma unroll
    for (int i = 0; i < 32; i += 8)
      tt[ty + i][tx] = f2bf(Wo[(size_t)(k0 + ty + i) * 768 + n0 + tx]);
    __syncthreads();
#pragma unroll
    for (int i = 0; i < 32; i += 8)
      WoT[(size_t)(n0 + ty + i) * 768 + k0 + tx] = tt[tx][ty + i];
  }
}

// ---------------------------------------------------------------------------
// A-stationary barrier-free GEMM: C[M,N] = A[M,768] @ Wt[N,768]^T + bias.
// Block = 32 A-rows staged ONCE into 48 KB gathered-chunk LDS (read-only
// afterwards -> NO barriers/vmcnt in the K-loop). W streams global->VGPR
// as B-fragments (L2-resident per XCD: 3.5 MB fits 4 MB). 4 waves x N-span
// (2304/4 or 768/4), chunks of 64 cols; per k-step: 4 W-loads + 2 lane-linear
// ds_reads + 8 MFMAs, dist-1 register prefetch, compiler-scheduled.
// Grid 512 blocks, 3 blocks/CU (12 waves/CU), all co-resident.
// MODE 0: A = x (f32, converted in prologue); outputs Q,K row-major bf16 +
//         V^T [B,H,HS,S] bf16.   MODE 1: A = att bf16; output f32.
// ---------------------------------------------------------------------------
template <int MODE>
__global__ __launch_bounds__(256, 3) void gemmAS(const float* __restrict__ xf,
                                                 const u16* __restrict__ Ab,
                                                 const u16* __restrict__ Wt,
                                                 const float* __restrict__ bias,
                                                 u16* __restrict__ O0, u16* __restrict__ O1,
                                                 u16* __restrict__ O2,
                                                 float* __restrict__ Of) {
  constexpr int NTOT = (MODE == 0) ? 2304 : 768;
  constexpr int NW = NTOT / 4;   // per-wave N span
  constexpr int NCH = NW / 64;   // 64-col chunks per wave: 9 / 3
  __shared__ u16 X[48 * 64 * 8];  // 48 KB: chunk c, slot l -> 16B at (c*64+l)*16
  const int tid = threadIdx.x;
  const int wid = tid >> 6, lane = tid & 63;
  const int lo = lane & 15, hi = lane >> 4;
  const int m0 = blockIdx.x * 32;

  // ---- prologue: stage A-tile (32 x 768) into gathered-chunk LDS (once)
#pragma unroll
  for (int s = 0; s < 12; ++s) {
    const int id = s * 256 + tid;          // 0..3071 slots
    const int c = id >> 6, l = id & 63;
    const int row = (c & 1) * 16 + (l & 15);
    const int k0 = (c >> 1) * 32 + (l >> 4) * 8;
    u16x8 v;
    if (MODE == 0) {
      const float4 a = *(const float4*)(xf + (size_t)(m0 + row) * 768 + k0);
      const float4 b = *(const float4*)(xf + (size_t)(m0 + row) * 768 + k0 + 4);
      v[0] = f2bf(a.x); v[1] = f2bf(a.y); v[2] = f2bf(a.z); v[3] = f2bf(a.w);
      v[4] = f2bf(b.x); v[5] = f2bf(b.y); v[6] = f2bf(b.z); v[7] = f2bf(b.w);
    } else {
      v = *(const u16x8*)(Ab + (size_t)(m0 + row) * 768 + k0);
    }
    *(u16x8*)&X[id * 8] = v;
  }
  __syncthreads();  // the only block-wide barrier

  // ---- per-chunk K=768 loop, barrier-free
  for (int ch = 0; ch < NCH; ++ch) {
    const int n0 = wid * NW + ch * 64;
    const u16* wp = Wt + (size_t)(n0 + lo) * 768 + hi * 8;  // + g*16*768 + k*32
    f32x4 acc[2][4] = {};
    bf16x8 ca0 = *(const bf16x8*)&X[(0 * 64 + lane) * 8];
    bf16x8 ca1 = *(const bf16x8*)&X[(1 * 64 + lane) * 8];
    bf16x8 cb[4];
#pragma unroll
    for (int g = 0; g < 4; ++g) cb[g] = *(const bf16x8*)(wp + (size_t)g * 16 * 768);
    for (int k = 0; k < 24; ++k) {
      bf16x8 na0, na1, nb[4];
      if (k + 1 < 24) {  // dist-1 prefetch: issue before this iter's MFMAs
        na0 = *(const bf16x8*)&X[(((k + 1) * 2 + 0) * 64 + lane) * 8];
        na1 = *(const bf16x8*)&X[(((k + 1) * 2 + 1) * 64 + lane) * 8];
#pragma unroll
        for (int g = 0; g < 4; ++g)
          nb[g] = *(const bf16x8*)(wp + (size_t)g * 16 * 768 + (k + 1) * 32);
      }
#pragma unroll
      for (int g = 0; g < 4; ++g) {
        acc[0][g] = MFMA16(ca0, cb[g], acc[0][g]);
        acc[1][g] = MFMA16(ca1, cb[g], acc[1][g]);
      }
      ca0 = na0;
      ca1 = na1;
#pragma unroll
      for (int g = 0; g < 4; ++g) cb[g] = nb[g];
    }
    // ---- chunk epilogue. C/D: col = lane&15, row = (lane>>4)*4 + r
#pragma unroll
    for (int g = 0; g < 4; ++g) {
      const int n = n0 + g * 16 + lo;
      const float bv = bias[n];
#pragma unroll
      for (int f = 0; f < 2; ++f) {
#pragma unroll
        for (int r = 0; r < 4; ++r) {
          const int m = m0 + f * 16 + hi * 4 + r;
          const float fv = acc[f][g][r] + bv;
          if (MODE == 0) {
            const u16 o = f2bf(fv);
            if (n < D_) {
              O0[(size_t)m * D_ + n] = o;  // Q row-major
            } else if (n < 2 * D_) {
              O1[(size_t)m * D_ + (n - D_)] = o;  // K row-major
            } else {
              const int np = n - 2 * D_;  // V -> V^T [B,H,HS,S]
              O2[(((size_t)(m >> 10) * H_ + (np >> 6)) * 64 + (np & 63)) * S_ + (m & 1023)] = o;
            }
          } else {
            Of[(size_t)m * D_ + n] = fv;  // f32 output
          }
        }
      }
    }
  }
}

// ---------------------------------------------------------------------------
// Flash attention v2 (swapped-operand 32x32 MFMA, in-register softmax).
// 1 block = (b, h, 128 q-rows), 4 waves x 32 q-rows. KV tiles of 32.
// ---------------------------------------------------------------------------
__global__ __launch_bounds__(256) void attn_fwd2(const u16* __restrict__ Qb,
                                                 const u16* __restrict__ Kb,
                                                 const u16* __restrict__ VTb,
                                                 u16* __restrict__ att) {
  __shared__ u16 Kl[2048];  // 4 KB: chunk (c*64 + hi1*32 + kv) * 16B
  __shared__ u16 Vl[2048];  // 4 KB: chunk ((kvch*2+dblk)*64 + hi1*32 + d31) * 16B
  const int tid = threadIdx.x;
  const int lane = tid & 63, wid = tid >> 6;
  const int l31 = lane & 31, hi1 = lane >> 5;
  // XCD-aware remap: co-locate the 8 q-blocks of one (b,h) on one XCD.
  const int L = blockIdx.x + 8 * (blockIdx.y + 12 * blockIdx.z);
  const int bx = (L >> 3) & 7;
  const int P = (L & 7) + 8 * (L >> 6);
  const int h = P % 12, b = P / 12;
  const int q0 = bx * 128;
  const int qw0 = q0 + wid * 32;
  const int qg = qw0 + l31;  // this lane's q-row
  const size_t rowbase = (size_t)b * S_;

  // Q fragments (B-operand of swapped QK^T): lane holds Q[qg][c*16+hi1*8+j]/8
  bf16x8 qf[4];
  {
    const u16* qp = Qb + (rowbase + qg) * D_ + h * 64 + hi1 * 8;
#pragma unroll
    for (int c = 0; c < 4; ++c) {
      bf16x8 v = *(const bf16x8*)(qp + c * 16);
#pragma unroll
      for (int j = 0; j < 8; ++j) v[j] = (short)f2bf(bf2f((u16)v[j]) * 0.125f);
      qf[c] = v;
    }
  }
  float mrun = -3.0e38f, lrun = 0.0f;
  f32x16 o0 = {}, o1 = {};

  // Staging: thread t's data lands at LDS byte t*16 (= wave base + lane*16).
  const u16* kgp =
      Kb + (rowbase + (tid & 31)) * D_ + h * 64 + (tid >> 6) * 16 + ((tid >> 5) & 1) * 8;
  const u16* vgp = VTb +
                   (((size_t)b * H_ + h) * 64 + ((tid >> 6) & 1) * 32 + (tid & 31)) * S_ +
                   (tid >> 7) * 16 + ((tid >> 5) & 1) * 8;
  char* kdst = (char*)Kl + wid * 1024;  // wave-uniform dest
  char* vdst = (char*)Vl + wid * 1024;
  const char* kbase = (const char*)Kl + lane * 16;
  const char* vbase = (const char*)Vl + lane * 16;

  const int kvend = q0 + 128;  // causal bound for this block
  for (int kv0 = 0; kv0 < kvend; kv0 += 32) {
    __syncthreads();  // prior tile's fragment reads complete
    GLD16(kgp + (size_t)kv0 * D_, kdst);
    GLD16(vgp + kv0, vdst);
    __syncthreads();  // staging visible
    if (kv0 > qw0 + 31) continue;  // fully masked for this wave (wave-uniform)

    // QK^T: 4 MFMAs over d-chunks of 16
    f32x16 s = {};
#pragma unroll
    for (int c = 0; c < 4; ++c) s = MFMA32(*(const bf16x8*)(kbase + c * 1024), qf[c], s);

    if (kv0 + 31 > qw0) {  // diagonal tile: causal mask
#pragma unroll
      for (int r = 0; r < 16; ++r) {
        const int kvg = kv0 + (r & 3) + 8 * (r >> 2) + 4 * hi1;
        if (kvg > qg) s[r] = -1.0e30f;
      }
    }
    // online softmax: in-lane reduce + 1 shfl to the partner half-row
    float rm = s[0];
#pragma unroll
    for (int r = 1; r < 16; ++r) rm = fmaxf(rm, s[r]);
    rm = fmaxf(rm, __shfl_xor(rm, 32));
    const float mn = fmaxf(mrun, rm);
    const float fr = __expf(mrun - mn);
    mrun = mn;
    float p[16];
    float rs = 0.0f;
#pragma unroll
    for (int r = 0; r < 16; ++r) {
      p[r] = __expf(s[r] - mn);
      rs += p[r];
    }
    rs += __shfl_xor(rs, 32);
    lrun = lrun * fr + rs;
#pragma unroll
    for (int r = 0; r < 16; ++r) {
      o0[r] *= fr;
      o1[r] *= fr;
    }
    // pack P to bf16 pairs; 4 shfls build both PV B-fragments in-register
    unsigned int pa[4], pb[4];
#pragma unroll
    for (int g = 0; g < 4; ++g) {
      pa[g] = (unsigned)f2bf(p[4 * g]) | ((unsigned)f2bf(p[4 * g + 1]) << 16);
      pb[g] = (unsigned)f2bf(p[4 * g + 2]) | ((unsigned)f2bf(p[4 * g + 3]) << 16);
    }
    const unsigned sa = __shfl_xor(hi1 ? pa[0] : pa[1], 32);
    const unsigned sb = __shfl_xor(hi1 ? pb[0] : pb[1], 32);
    const unsigned sc = __shfl_xor(hi1 ? pa[2] : pa[3], 32);
    const unsigned sd = __shfl_xor(hi1 ? pb[2] : pb[3], 32);
    const uint4 w0 = hi1 ? make_uint4(sa, sb, pa[1], pb[1]) : make_uint4(pa[0], pb[0], sa, sb);
    const uint4 w1 = hi1 ? make_uint4(sc, sd, pa[3], pb[3]) : make_uint4(pa[2], pb[2], sc, sd);
    bf16x8 pf0, pf1;
    __builtin_memcpy(&pf0, &w0, 16);
    __builtin_memcpy(&pf1, &w1, 16);
    // PV: O^T += V^T_chunk . P^T  (4 MFMAs: kvchunk x dblk)
    o0 = MFMA32(*(const bf16x8*)(vbase + 0 * 1024), pf0, o0);
    o1 = MFMA32(*(const bf16x8*)(vbase + 1 * 1024), pf0, o1);
    o0 = MFMA32(*(const bf16x8*)(vbase + 2 * 1024), pf1, o0);
    o1 = MFMA32(*(const bf16x8*)(vbase + 3 * 1024), pf1, o1);
  }
  // epilogue: lane owns q; rows are d-offsets (r&3)+8*(r>>2)+4*hi1
  const float inv = 1.0f / lrun;
  u16* op = att + (rowbase + qg) * D_ + h * 64;
#pragma unroll
  for (int g = 0; g < 4; ++g) {
    u16x4 v0, v1;
#pragma unroll
    for (int j = 0; j < 4; ++j) {
      v0[j] = f2bf(o0[4 * g + j] * inv);
      v1[j] = f2bf(o1[4 * g + j] * inv);
    }
    *(u16x4*)(op + 8 * g + 4 * hi1) = v0;
    *(u16x4*)(op + 32 + 8 * g + 4 * hi1) = v1;
  }
}

// ---------------------------------------------------------------------------
extern "C" void kernel_launch(void* const* d_in, const int* in_sizes, int n_in, void* d_out,
                              int out_size, void* d_ws, size_t ws_size, hipStream_t stream) {
  // Assign inputs by unique element count (robust to input ordering).
  const float *x = nullptr, *Wqkv = nullptr, *bqkv = nullptr, *Wo = nullptr, *bo = nullptr;
  for (int i = 0; i < n_in; ++i) {
    switch (in_sizes[i]) {
      case 16384 * 768:  x = (const float*)d_in[i]; break;     // [16,1024,768]
      case 768 * 2304:   Wqkv = (const float*)d_in[i]; break;  // [768,2304]
      case 2304:         bqkv = (const float*)d_in[i]; break;  // [2304]
      case 768 * 768:    Wo = (const float*)d_in[i]; break;    // [768,768]
      case 768:          bo = (const float*)d_in[i]; break;    // [768]
    }
  }
  float* out = (float*)d_out;  // [16,1024,768] FLOAT32

  char* ws = (char*)d_ws;
  u16* WqkvT = (u16*)(ws);              // 2304*768*2  = 3,538,944
  u16* WoT = (u16*)(ws + 3538944);      // 768*768*2   = 1,179,648
  u16* Qb = (u16*)(ws + 4718592);       // 16384*768*2 = 25,165,824
  u16* Kb = (u16*)(ws + 29884416);      // 25,165,824
  u16* VT = (u16*)(ws + 55050240);      // 25,165,824 -> ws total 80,216,064 B
  u16* att = Qb;  // alias: attn block reads its own Q region before writing

  prep<<<2304, 256, 0, stream>>>(Wqkv, WqkvT, Wo, WoT);
  gemmAS<0><<<512, 256, 0, stream>>>(x, nullptr, WqkvT, bqkv, Qb, Kb, VT, nullptr);
  attn_fwd2<<<dim3(8, H_, B_), 256, 0, stream>>>(Qb, Kb, VT, att);
  gemmAS<1><<<512, 256, 0, stream>>>(nullptr, att, WoT, bo, nullptr, nullptr, nullptr, out);
}

// Round 14
// 260.105 us; speedup vs baseline: 2.3509x; 2.3509x over previous
//
#include <hip/hip_runtime.h>
#include <stdint.h>

typedef unsigned short u16;
typedef __attribute__((ext_vector_type(8))) short bf16x8;
typedef __attribute__((ext_vector_type(8))) u16 u16x8;
typedef __attribute__((ext_vector_type(4))) u16 u16x4;
typedef __attribute__((ext_vector_type(4))) float f32x4;
typedef __attribute__((ext_vector_type(16))) float f32x16;

#define B_ 16
#define S_ 1024
#define D_ 768
#define H_ 12

__device__ __forceinline__ float bf2f(u16 u) {
  unsigned int x = ((unsigned int)u) << 16;
  float f;
  __builtin_memcpy(&f, &x, 4);
  return f;
}
__device__ __forceinline__ u16 f2bf(float f) {
  unsigned int x;
  __builtin_memcpy(&x, &f, 4);
  x += 0x7fffu + ((x >> 16) & 1u);
  return (u16)(x >> 16);
}

#define MFMA16(a, b, c) __builtin_amdgcn_mfma_f32_16x16x32_bf16((a), (b), (c), 0, 0, 0)
#define MFMA32(a, b, c) __builtin_amdgcn_mfma_f32_32x32x16_bf16((a), (b), (c), 0, 0, 0)

#define GLD16(g, l)                                              \
  __builtin_amdgcn_global_load_lds(                              \
      (const __attribute__((address_space(1))) void*)(g),        \
      (__attribute__((address_space(3))) void*)(l), 16, 0, 0)

// ---------------------------------------------------------------------------
// Fused prologue: f32->bf16 convert of x + two transpose-convert weights.
// ---------------------------------------------------------------------------
__global__ __launch_bounds__(256) void prep(const float* __restrict__ x,
                                            u16* __restrict__ xb,
                                            const float* __restrict__ Wqkv,
                                            u16* __restrict__ WqkvT,
                                            const float* __restrict__ Wo,
                                            u16* __restrict__ WoT) {
  __shared__ u16 tt[32][33];
  const int gx = blockIdx.x;
  const int tid = threadIdx.x;
  if (gx < 6144) {  // cvt x: 16384*768/8 = 1,572,864 vec8 elems, exact
    const int i = gx * 256 + tid;
    const float4 a = *(const float4*)(x + (size_t)i * 8);
    const float4 b = *(const float4*)(x + (size_t)i * 8 + 4);
    u16x8 o;
    o[0] = f2bf(a.x); o[1] = f2bf(a.y); o[2] = f2bf(a.z); o[3] = f2bf(a.w);
    o[4] = f2bf(b.x); o[5] = f2bf(b.y); o[6] = f2bf(b.z); o[7] = f2bf(b.w);
    *(u16x8*)(xb + (size_t)i * 8) = o;
  } else if (gx < 6144 + 1728) {  // Wqkv [768,2304] -> WqkvT [2304,768]
    const int t = gx - 6144;
    const int n0 = (t % 72) * 32, k0 = (t / 72) * 32;
    const int tx = tid & 31, ty = tid >> 5;
#pragma unroll
    for (int i = 0; i < 32; i += 8)
      tt[ty + i][tx] = f2bf(Wqkv[(size_t)(k0 + ty + i) * 2304 + n0 + tx]);
    __syncthreads();
#pragma unroll
    for (int i = 0; i < 32; i += 8)
      WqkvT[(size_t)(n0 + ty + i) * 768 + k0 + tx] = tt[tx][ty + i];
  } else {  // Wo [768,768] -> WoT [768,768]
    const int t = gx - 7872;
    const int n0 = (t % 24) * 32, k0 = (t / 24) * 32;
    const int tx = tid & 31, ty = tid >> 5;
#pragma unroll
    for (int i = 0; i < 32; i += 8)
      tt[ty + i][tx] = f2bf(Wo[(size_t)(k0 + ty + i) * 768 + n0 + tx]);
    __syncthreads();
#pragma unroll
    for (int i = 0; i < 32; i += 8)
      WoT[(size_t)(n0 + ty + i) * 768 + k0 + tx] = tt[tx][ty + i];
  }
}

// ---------------------------------------------------------------------------
// 128x128x64 MFMA GEMM (BK=64: half the barriers/epochs of r9's BK=32).
// 4 waves (2x2), per-wave 64x64 out; per K-tile: 16 ds_read_b128 + 32 MFMA
// per wave, 8 GLD16 staging. Dist-1 double-buffer (r7-proven), vmcnt(0) only
// after compute (next tile's loads fly under the 32-MFMA phase).
// LDS rows are 128 B -> XOR-swizzle (byte ^= (row&7)<<4) applied identically
// on the pre-swizzled GLOBAL source (stage side) and the ds_read address
// (read side); global reads stay 128B-coalesced (8 lanes x 16B permuted
// within each 128B row segment). 64 KB LDS -> 2 blocks/CU.
// MODE 0: QKV epilogue -> Q,K row-major bf16 + V^T [B,H,HS,S] bf16
// MODE 1: f32 row-major Of[M,N]
// ---------------------------------------------------------------------------
template <int MODE>
__global__ __launch_bounds__(256, 2) void gemm_bt(const u16* __restrict__ A,
                                                  const u16* __restrict__ Bt,
                                                  const float* __restrict__ bias,
                                                  u16* __restrict__ O0, u16* __restrict__ O1,
                                                  u16* __restrict__ O2, float* __restrict__ Of,
                                                  int M, int N, int K) {
  __shared__ u16 Al[2 * 128 * 64];  // 2 bufs x 16 KB
  __shared__ u16 Bl[2 * 128 * 64];
  const int tid = threadIdx.x;
  const int wid = tid >> 6, lane = tid & 63;
  const int lo = lane & 15, hi = lane >> 4;
  const int wr = wid >> 1, wc = wid & 1;
  const int m0 = blockIdx.x * 128, n0 = blockIdx.y * 128;
  const int T = K >> 6;  // 12

  // Staging geometry: chunk c (0..15) = rows c*8..c*8+8 of the 128x64 tile.
  // Wave w stages chunks {w+4q}; lane l: row = c*8 + (l>>3), within-row 16B
  // slot = (l&7) ^ (row&7)  [the XOR pre-swizzle].
  const int sr = lane >> 3;                  // row within 8-row chunk (=row&7)
  const int kk = ((lane & 7) ^ sr) * 8;      // pre-swizzled k element offset
  const u16* const asrc = A + (size_t)(m0 + wid * 8 + sr) * K + kk;
  const u16* const bsrc = Bt + (size_t)(n0 + wid * 8 + sr) * K + kk;

#define STAGE(kt, buf)                                                          \
  do {                                                                          \
    const size_t _k = (size_t)(kt) * 64;                                        \
    GLD16(asrc + _k, (char*)Al + (buf) * 16384 + (wid) * 1024);                 \
    GLD16(asrc + (size_t)32 * K + _k, (char*)Al + (buf) * 16384 + (wid + 4) * 1024);  \
    GLD16(asrc + (size_t)64 * K + _k, (char*)Al + (buf) * 16384 + (wid + 8) * 1024);  \
    GLD16(asrc + (size_t)96 * K + _k, (char*)Al + (buf) * 16384 + (wid + 12) * 1024); \
    GLD16(bsrc + _k, (char*)Bl + (buf) * 16384 + (wid) * 1024);                 \
    GLD16(bsrc + (size_t)32 * K + _k, (char*)Bl + (buf) * 16384 + (wid + 4) * 1024);  \
    GLD16(bsrc + (size_t)64 * K + _k, (char*)Bl + (buf) * 16384 + (wid + 8) * 1024);  \
    GLD16(bsrc + (size_t)96 * K + _k, (char*)Bl + (buf) * 16384 + (wid + 12) * 1024); \
  } while (0)

  f32x4 acc[4][4] = {};

  STAGE(0, 0);
  asm volatile("s_waitcnt vmcnt(0)" ::: "memory");
  __builtin_amdgcn_s_barrier();

  for (int t = 0; t < T; ++t) {
    if (t + 1 < T) STAGE(t + 1, (t + 1) & 1);  // flies under the 32-MFMA phase
    const int cb = (t & 1) * 16384;  // byte offset of current buffer
    const int swz = (lo & 7) << 4;   // read-side XOR (row&7 == lo&7)
    bf16x8 af[4][2], bfv[4][2];
#pragma unroll
    for (int i = 0; i < 4; ++i)
#pragma unroll
      for (int s = 0; s < 2; ++s)
        af[i][s] = *(const bf16x8*)((const char*)Al + cb + (wr * 64 + i * 16 + lo) * 128 +
                                    ((s * 64 + hi * 16) ^ swz));
#pragma unroll
    for (int j = 0; j < 4; ++j)
#pragma unroll
      for (int s = 0; s < 2; ++s)
        bfv[j][s] = *(const bf16x8*)((const char*)Bl + cb + (wc * 64 + j * 16 + lo) * 128 +
                                     ((s * 64 + hi * 16) ^ swz));
    __builtin_amdgcn_s_setprio(1);
#pragma unroll
    for (int i = 0; i < 4; ++i)
#pragma unroll
      for (int j = 0; j < 4; ++j) {
        acc[i][j] = MFMA16(af[i][0], bfv[j][0], acc[i][j]);
        acc[i][j] = MFMA16(af[i][1], bfv[j][1], acc[i][j]);
      }
    __builtin_amdgcn_s_setprio(0);
    if (t + 1 < T) asm volatile("s_waitcnt vmcnt(0)" ::: "memory");
    __builtin_amdgcn_s_barrier();
  }
#undef STAGE
  // Epilogue. C/D: col = lane&15, row = (lane>>4)*4 + r  [verified m89/m91]
#pragma unroll
  for (int g = 0; g < 4; ++g) {
    const int n = n0 + wc * 64 + g * 16 + lo;
    const float bv = bias[n];
#pragma unroll
    for (int f = 0; f < 4; ++f) {
#pragma unroll
      for (int r = 0; r < 4; ++r) {
        const int m = m0 + wr * 64 + f * 16 + hi * 4 + r;
        const float fv = acc[f][g][r] + bv;
        if (MODE == 0) {
          const u16 o = f2bf(fv);
          if (n0 < D_) {
            O0[(size_t)m * D_ + n] = o;  // Q row-major
          } else if (n0 < 2 * D_) {
            O1[(size_t)m * D_ + (n - D_)] = o;  // K row-major
          } else {
            const int np = n - 2 * D_;  // V -> V^T [B,H,HS,S]
            O2[(((size_t)(m >> 10) * H_ + (np >> 6)) * 64 + (np & 63)) * S_ + (m & 1023)] = o;
          }
        } else {
          Of[(size_t)m * N + n] = fv;  // f32 output
        }
      }
    }
  }
}

// ---------------------------------------------------------------------------
// Flash attention v2 (swapped-operand 32x32 MFMA, in-register softmax).
// 1 block = (b, h, 128 q-rows), 4 waves x 32 q-rows. KV tiles of 32.
// ---------------------------------------------------------------------------
__global__ __launch_bounds__(256) void attn_fwd2(const u16* __restrict__ Qb,
                                                 const u16* __restrict__ Kb,
                                                 const u16* __restrict__ VTb,
                                                 u16* __restrict__ att) {
  __shared__ u16 Kl[2048];  // 4 KB: chunk (c*64 + hi1*32 + kv) * 16B
  __shared__ u16 Vl[2048];  // 4 KB: chunk ((kvch*2+dblk)*64 + hi1*32 + d31) * 16B
  const int tid = threadIdx.x;
  const int lane = tid & 63, wid = tid >> 6;
  const int l31 = lane & 31, hi1 = lane >> 5;
  // XCD-aware remap: co-locate the 8 q-blocks of one (b,h) on one XCD.
  const int L = blockIdx.x + 8 * (blockIdx.y + 12 * blockIdx.z);
  const int bx = (L >> 3) & 7;
  const int P = (L & 7) + 8 * (L >> 6);
  const int h = P % 12, b = P / 12;
  const int q0 = bx * 128;
  const int qw0 = q0 + wid * 32;
  const int qg = qw0 + l31;  // this lane's q-row
  const size_t rowbase = (size_t)b * S_;

  // Q fragments (B-operand of swapped QK^T): lane holds Q[qg][c*16+hi1*8+j]/8
  bf16x8 qf[4];
  {
    const u16* qp = Qb + (rowbase + qg) * D_ + h * 64 + hi1 * 8;
#pragma unroll
    for (int c = 0; c < 4; ++c) {
      bf16x8 v = *(const bf16x8*)(qp + c * 16);
#pragma unroll
      for (int j = 0; j < 8; ++j) v[j] = (short)f2bf(bf2f((u16)v[j]) * 0.125f);
      qf[c] = v;
    }
  }
  float mrun = -3.0e38f, lrun = 0.0f;
  f32x16 o0 = {}, o1 = {};

  // Staging: thread t's data lands at LDS byte t*16 (= wave base + lane*16).
  const u16* kgp =
      Kb + (rowbase + (tid & 31)) * D_ + h * 64 + (tid >> 6) * 16 + ((tid >> 5) & 1) * 8;
  const u16* vgp = VTb +
                   (((size_t)b * H_ + h) * 64 + ((tid >> 6) & 1) * 32 + (tid & 31)) * S_ +
                   (tid >> 7) * 16 + ((tid >> 5) & 1) * 8;
  char* kdst = (char*)Kl + wid * 1024;  // wave-uniform dest
  char* vdst = (char*)Vl + wid * 1024;
  const char* kbase = (const char*)Kl + lane * 16;
  const char* vbase = (const char*)Vl + lane * 16;

  const int kvend = q0 + 128;  // causal bound for this block
  for (int kv0 = 0; kv0 < kvend; kv0 += 32) {
    __syncthreads();  // prior tile's fragment reads complete
    GLD16(kgp + (size_t)kv0 * D_, kdst);
    GLD16(vgp + kv0, vdst);
    __syncthreads();  // staging visible
    if (kv0 > qw0 + 31) continue;  // fully masked for this wave (wave-uniform)

    // QK^T: 4 MFMAs over d-chunks of 16
    f32x16 s = {};
#pragma unroll
    for (int c = 0; c < 4; ++c) s = MFMA32(*(const bf16x8*)(kbase + c * 1024), qf[c], s);

    if (kv0 + 31 > qw0) {  // diagonal tile: causal mask
#pragma unroll
      for (int r = 0; r < 16; ++r) {
        const int kvg = kv0 + (r & 3) + 8 * (r >> 2) + 4 * hi1;
        if (kvg > qg) s[r] = -1.0e30f;
      }
    }
    // online softmax: in-lane reduce + 1 shfl to the partner half-row
    float rm = s[0];
#pragma unroll
    for (int r = 1; r < 16; ++r) rm = fmaxf(rm, s[r]);
    rm = fmaxf(rm, __shfl_xor(rm, 32));
    const float mn = fmaxf(mrun, rm);
    const float fr = __expf(mrun - mn);
    mrun = mn;
    float p[16];
    float rs = 0.0f;
#pragma unroll
    for (int r = 0; r < 16; ++r) {
      p[r] = __expf(s[r] - mn);
      rs += p[r];
    }
    rs += __shfl_xor(rs, 32);
    lrun = lrun * fr + rs;
#pragma unroll
    for (int r = 0; r < 16; ++r) {
      o0[r] *= fr;
      o1[r] *= fr;
    }
    // pack P to bf16 pairs; 4 shfls build both PV B-fragments in-register
    unsigned int pa[4], pb[4];
#pragma unroll
    for (int g = 0; g < 4; ++g) {
      pa[g] = (unsigned)f2bf(p[4 * g]) | ((unsigned)f2bf(p[4 * g + 1]) << 16);
      pb[g] = (unsigned)f2bf(p[4 * g + 2]) | ((unsigned)f2bf(p[4 * g + 3]) << 16);
    }
    const unsigned sa = __shfl_xor(hi1 ? pa[0] : pa[1], 32);
    const unsigned sb = __shfl_xor(hi1 ? pb[0] : pb[1], 32);
    const unsigned sc = __shfl_xor(hi1 ? pa[2] : pa[3], 32);
    const unsigned sd = __shfl_xor(hi1 ? pb[2] : pb[3], 32);
    const uint4 w0 = hi1 ? make_uint4(sa, sb, pa[1], pb[1]) : make_uint4(pa[0], pb[0], sa, sb);
    const uint4 w1 = hi1 ? make_uint4(sc, sd, pa[3], pb[3]) : make_uint4(pa[2], pb[2], sc, sd);
    bf16x8 pf0, pf1;
    __builtin_memcpy(&pf0, &w0, 16);
    __builtin_memcpy(&pf1, &w1, 16);
    // PV: O^T += V^T_chunk . P^T  (4 MFMAs: kvchunk x dblk)
    o0 = MFMA32(*(const bf16x8*)(vbase + 0 * 1024), pf0, o0);
    o1 = MFMA32(*(const bf16x8*)(vbase + 1 * 1024), pf0, o1);
    o0 = MFMA32(*(const bf16x8*)(vbase + 2 * 1024), pf1, o0);
    o1 = MFMA32(*(const bf16x8*)(vbase + 3 * 1024), pf1, o1);
  }
  // epilogue: lane owns q; rows are d-offsets (r&3)+8*(r>>2)+4*hi1
  const float inv = 1.0f / lrun;
  u16* op = att + (rowbase + qg) * D_ + h * 64;
#pragma unroll
  for (int g = 0; g < 4; ++g) {
    u16x4 v0, v1;
#pragma unroll
    for (int j = 0; j < 4; ++j) {
      v0[j] = f2bf(o0[4 * g + j] * inv);
      v1[j] = f2bf(o1[4 * g + j] * inv);
    }
    *(u16x4*)(op + 8 * g + 4 * hi1) = v0;
    *(u16x4*)(op + 32 + 8 * g + 4 * hi1) = v1;
  }
}

// ---------------------------------------------------------------------------
extern "C" void kernel_launch(void* const* d_in, const int* in_sizes, int n_in, void* d_out,
                              int out_size, void* d_ws, size_t ws_size, hipStream_t stream) {
  // Assign inputs by unique element count (robust to input ordering).
  const float *x = nullptr, *Wqkv = nullptr, *bqkv = nullptr, *Wo = nullptr, *bo = nullptr;
  for (int i = 0; i < n_in; ++i) {
    switch (in_sizes[i]) {
      case 16384 * 768:  x = (const float*)d_in[i]; break;     // [16,1024,768]
      case 768 * 2304:   Wqkv = (const float*)d_in[i]; break;  // [768,2304]
      case 2304:         bqkv = (const float*)d_in[i]; break;  // [2304]
      case 768 * 768:    Wo = (const float*)d_in[i]; break;    // [768,768]
      case 768:          bo = (const float*)d_in[i]; break;    // [768]
    }
  }
  float* out = (float*)d_out;  // [16,1024,768] FLOAT32

  char* ws = (char*)d_ws;
  u16* WqkvT = (u16*)(ws);              // 2304*768*2  = 3,538,944
  u16* WoT = (u16*)(ws + 3538944);      // 768*768*2   = 1,179,648
  u16* Qb = (u16*)(ws + 4718592);       // 16384*768*2 = 25,165,824
  u16* Kb = (u16*)(ws + 29884416);      // 25,165,824
  u16* VT = (u16*)(ws + 55050240);      // 25,165,824 -> ws total 80,216,064 B
  u16* xb = (u16*)d_out;  // bf16 x staged in d_out; dead before final GEMM
  u16* att = Qb;          // alias: attn block reads its own Q region first

  prep<<<8448, 256, 0, stream>>>(x, xb, Wqkv, WqkvT, Wo, WoT);
  gemm_bt<0><<<dim3(128, 18), 256, 0, stream>>>(xb, WqkvT, bqkv, Qb, Kb, VT, nullptr,
                                                16384, 2304, 768);
  attn_fwd2<<<dim3(8, H_, B_), 256, 0, stream>>>(Qb, Kb, VT, att);
  gemm_bt<1><<<dim3(128, 6), 256, 0, stream>>>(att, WoT, bo, nullptr, nullptr, nullptr, out,
                                               16384, 768, 768);
}

// Round 15
// 239.688 us; speedup vs baseline: 2.5511x; 1.0852x over previous
//
#include <hip/hip_runtime.h>
#include <stdint.h>

typedef unsigned short u16;
typedef __attribute__((ext_vector_type(8))) short bf16x8;
typedef __attribute__((ext_vector_type(8))) u16 u16x8;
typedef __attribute__((ext_vector_type(4))) u16 u16x4;
typedef __attribute__((ext_vector_type(4))) float f32x4;
typedef __attribute__((ext_vector_type(16))) float f32x16;

#define B_ 16
#define S_ 1024
#define D_ 768
#define H_ 12

__device__ __forceinline__ float bf2f(u16 u) {
  unsigned int x = ((unsigned int)u) << 16;
  float f;
  __builtin_memcpy(&f, &x, 4);
  return f;
}
__device__ __forceinline__ u16 f2bf(float f) {
  unsigned int x;
  __builtin_memcpy(&x, &f, 4);
  x += 0x7fffu + ((x >> 16) & 1u);
  return (u16)(x >> 16);
}

#define MFMA16(a, b, c) __builtin_amdgcn_mfma_f32_16x16x32_bf16((a), (b), (c), 0, 0, 0)
#define MFMA32(a, b, c) __builtin_amdgcn_mfma_f32_32x32x16_bf16((a), (b), (c), 0, 0, 0)

#define GLD16(g, l)                                              \
  __builtin_amdgcn_global_load_lds(                              \
      (const __attribute__((address_space(1))) void*)(g),        \
      (__attribute__((address_space(3))) void*)(l), 16, 0, 0)

// ---------------------------------------------------------------------------
// Fused prologue: f32->bf16 convert of x + two transpose-convert weights.
// ---------------------------------------------------------------------------
__global__ __launch_bounds__(256) void prep(const float* __restrict__ x,
                                            u16* __restrict__ xb,
                                            const float* __restrict__ Wqkv,
                                            u16* __restrict__ WqkvT,
                                            const float* __restrict__ Wo,
                                            u16* __restrict__ WoT) {
  __shared__ u16 tt[32][33];
  const int gx = blockIdx.x;
  const int tid = threadIdx.x;
  if (gx < 6144) {  // cvt x: 16384*768/8 = 1,572,864 vec8 elems, exact
    const int i = gx * 256 + tid;
    const float4 a = *(const float4*)(x + (size_t)i * 8);
    const float4 b = *(const float4*)(x + (size_t)i * 8 + 4);
    u16x8 o;
    o[0] = f2bf(a.x); o[1] = f2bf(a.y); o[2] = f2bf(a.z); o[3] = f2bf(a.w);
    o[4] = f2bf(b.x); o[5] = f2bf(b.y); o[6] = f2bf(b.z); o[7] = f2bf(b.w);
    *(u16x8*)(xb + (size_t)i * 8) = o;
  } else if (gx < 6144 + 1728) {  // Wqkv [768,2304] -> WqkvT [2304,768]
    const int t = gx - 6144;
    const int n0 = (t % 72) * 32, k0 = (t / 72) * 32;
    const int tx = tid & 31, ty = tid >> 5;
#pragma unroll
    for (int i = 0; i < 32; i += 8)
      tt[ty + i][tx] = f2bf(Wqkv[(size_t)(k0 + ty + i) * 2304 + n0 + tx]);
    __syncthreads();
#pragma unroll
    for (int i = 0; i < 32; i += 8)
      WqkvT[(size_t)(n0 + ty + i) * 768 + k0 + tx] = tt[tx][ty + i];
  } else {  // Wo [768,768] -> WoT [768,768]
    const int t = gx - 7872;
    const int n0 = (t % 24) * 32, k0 = (t / 24) * 32;
    const int tx = tid & 31, ty = tid >> 5;
#pragma unroll
    for (int i = 0; i < 32; i += 8)
      tt[ty + i][tx] = f2bf(Wo[(size_t)(k0 + ty + i) * 768 + n0 + tx]);
    __syncthreads();
#pragma unroll
    for (int i = 0; i < 32; i += 8)
      WoT[(size_t)(n0 + ty + i) * 768 + k0 + tx] = tt[tx][ty + i];
  }
}

// ---------------------------------------------------------------------------
// 128x128x64 MFMA GEMM (r14 inner loop, unchanged) + XCD-STRIPE SCHEDULE (T1).
// 1D grid, bid -> xcd = bid&7, idx = bid>>3; XCD k owns M-stripe of 16
// m-tiles x all NBT n-tiles, nb fastest:
//   mb = xcd*16 + idx/NBT, nb = idx%NBT.
// Effect: per-XCD L2 holds the full B (W^T <= 3.5 MB) + the active A panels
// (A panel reused across NBT consecutive work items) -> staged-operand
// traffic external to L2 drops ~16x (the r14 bottleneck: 884 MB of
// L3-served global->LDS staging).
// Dist-1 double-buffer, XOR-swizzled LDS (conflict-free, verified r14).
// MODE 0: QKV epilogue -> Q,K row-major bf16 + V^T [B,H,HS,S] bf16 (u16x4-
// grouped V stores). MODE 1: f32 row-major Of[M,N].
// ---------------------------------------------------------------------------
template <int MODE>
__global__ __launch_bounds__(256, 2) void gemm_bt(const u16* __restrict__ A,
                                                  const u16* __restrict__ Bt,
                                                  const float* __restrict__ bias,
                                                  u16* __restrict__ O0, u16* __restrict__ O1,
                                                  u16* __restrict__ O2, float* __restrict__ Of,
                                                  int M, int N, int K, int NBT) {
  __shared__ u16 Al[2 * 128 * 64];  // 2 bufs x 16 KB
  __shared__ u16 Bl[2 * 128 * 64];
  const int tid = threadIdx.x;
  const int wid = tid >> 6, lane = tid & 63;
  const int lo = lane & 15, hi = lane >> 4;
  const int wr = wid >> 1, wc = wid & 1;
  // XCD-stripe schedule
  const int bid = blockIdx.x;
  const int xcd = bid & 7, idx = bid >> 3;
  const int mb = xcd * 16 + idx / NBT;
  const int nb = idx % NBT;
  const int m0 = mb * 128, n0 = nb * 128;
  const int T = K >> 6;  // 12

  // Staging geometry: chunk c (0..15) = rows c*8..c*8+8 of the 128x64 tile.
  // Wave w stages chunks {w+4q}; lane l: row = c*8 + (l>>3), within-row 16B
  // slot = (l&7) ^ (row&7)  [the XOR pre-swizzle].
  const int sr = lane >> 3;                  // row within 8-row chunk (=row&7)
  const int kk = ((lane & 7) ^ sr) * 8;      // pre-swizzled k element offset
  const u16* const asrc = A + (size_t)(m0 + wid * 8 + sr) * K + kk;
  const u16* const bsrc = Bt + (size_t)(n0 + wid * 8 + sr) * K + kk;

#define STAGE(kt, buf)                                                          \
  do {                                                                          \
    const size_t _k = (size_t)(kt) * 64;                                        \
    GLD16(asrc + _k, (char*)Al + (buf) * 16384 + (wid) * 1024);                 \
    GLD16(asrc + (size_t)32 * K + _k, (char*)Al + (buf) * 16384 + (wid + 4) * 1024);  \
    GLD16(asrc + (size_t)64 * K + _k, (char*)Al + (buf) * 16384 + (wid + 8) * 1024);  \
    GLD16(asrc + (size_t)96 * K + _k, (char*)Al + (buf) * 16384 + (wid + 12) * 1024); \
    GLD16(bsrc + _k, (char*)Bl + (buf) * 16384 + (wid) * 1024);                 \
    GLD16(bsrc + (size_t)32 * K + _k, (char*)Bl + (buf) * 16384 + (wid + 4) * 1024);  \
    GLD16(bsrc + (size_t)64 * K + _k, (char*)Bl + (buf) * 16384 + (wid + 8) * 1024);  \
    GLD16(bsrc + (size_t)96 * K + _k, (char*)Bl + (buf) * 16384 + (wid + 12) * 1024); \
  } while (0)

  f32x4 acc[4][4] = {};

  STAGE(0, 0);
  asm volatile("s_waitcnt vmcnt(0)" ::: "memory");
  __builtin_amdgcn_s_barrier();

  for (int t = 0; t < T; ++t) {
    if (t + 1 < T) STAGE(t + 1, (t + 1) & 1);  // flies under the 32-MFMA phase
    const int cb = (t & 1) * 16384;  // byte offset of current buffer
    const int swz = (lo & 7) << 4;   // read-side XOR (row&7 == lo&7)
    bf16x8 af[4][2], bfv[4][2];
#pragma unroll
    for (int i = 0; i < 4; ++i)
#pragma unroll
      for (int s = 0; s < 2; ++s)
        af[i][s] = *(const bf16x8*)((const char*)Al + cb + (wr * 64 + i * 16 + lo) * 128 +
                                    ((s * 64 + hi * 16) ^ swz));
#pragma unroll
    for (int j = 0; j < 4; ++j)
#pragma unroll
      for (int s = 0; s < 2; ++s)
        bfv[j][s] = *(const bf16x8*)((const char*)Bl + cb + (wc * 64 + j * 16 + lo) * 128 +
                                     ((s * 64 + hi * 16) ^ swz));
    __builtin_amdgcn_s_setprio(1);
#pragma unroll
    for (int i = 0; i < 4; ++i)
#pragma unroll
      for (int j = 0; j < 4; ++j) {
        acc[i][j] = MFMA16(af[i][0], bfv[j][0], acc[i][j]);
        acc[i][j] = MFMA16(af[i][1], bfv[j][1], acc[i][j]);
      }
    __builtin_amdgcn_s_setprio(0);
    if (t + 1 < T) asm volatile("s_waitcnt vmcnt(0)" ::: "memory");
    __builtin_amdgcn_s_barrier();
  }
#undef STAGE
  // Epilogue. C/D: col = lane&15, row = (lane>>4)*4 + r  [verified m89/m91]
  if (MODE == 0 && n0 >= 2 * D_) {
    // V region (block-uniform): V^T [B,H,64,S]; r-quad = 4 consecutive m ->
    // one u16x4 (8B) store instead of four 2B scatters.
#pragma unroll
    for (int g = 0; g < 4; ++g) {
      const int n = n0 + wc * 64 + g * 16 + lo;
      const float bv = bias[n];
      const int np = n - 2 * D_;
#pragma unroll
      for (int f = 0; f < 4; ++f) {
        const int m = m0 + wr * 64 + f * 16 + hi * 4;  // r = 0 of the quad
        u16x4 q;
#pragma unroll
        for (int r = 0; r < 4; ++r) q[r] = f2bf(acc[f][g][r] + bv);
        *(u16x4*)&O2[(((size_t)(m >> 10) * H_ + (np >> 6)) * 64 + (np & 63)) * S_ +
                     (m & 1023)] = q;
      }
    }
  } else {
#pragma unroll
    for (int g = 0; g < 4; ++g) {
      const int n = n0 + wc * 64 + g * 16 + lo;
      const float bv = bias[n];
#pragma unroll
      for (int f = 0; f < 4; ++f) {
#pragma unroll
        for (int r = 0; r < 4; ++r) {
          const int m = m0 + wr * 64 + f * 16 + hi * 4 + r;
          const float fv = acc[f][g][r] + bv;
          if (MODE == 0) {
            const u16 o = f2bf(fv);
            if (n0 < D_) {
              O0[(size_t)m * D_ + n] = o;  // Q row-major
            } else {
              O1[(size_t)m * D_ + (n - D_)] = o;  // K row-major
            }
          } else {
            Of[(size_t)m * N + n] = fv;  // f32 output
          }
        }
      }
    }
  }
}

// ---------------------------------------------------------------------------
// Flash attention v2 (swapped-operand 32x32 MFMA, in-register softmax).
// 1 block = (b, h, 128 q-rows), 4 waves x 32 q-rows. KV tiles of 32.
// ---------------------------------------------------------------------------
__global__ __launch_bounds__(256) void attn_fwd2(const u16* __restrict__ Qb,
                                                 const u16* __restrict__ Kb,
                                                 const u16* __restrict__ VTb,
                                                 u16* __restrict__ att) {
  __shared__ u16 Kl[2048];  // 4 KB: chunk (c*64 + hi1*32 + kv) * 16B
  __shared__ u16 Vl[2048];  // 4 KB: chunk ((kvch*2+dblk)*64 + hi1*32 + d31) * 16B
  const int tid = threadIdx.x;
  const int lane = tid & 63, wid = tid >> 6;
  const int l31 = lane & 31, hi1 = lane >> 5;
  // XCD-aware remap: co-locate the 8 q-blocks of one (b,h) on one XCD.
  const int L = blockIdx.x + 8 * (blockIdx.y + 12 * blockIdx.z);
  const int bx = (L >> 3) & 7;
  const int P = (L & 7) + 8 * (L >> 6);
  const int h = P % 12, b = P / 12;
  const int q0 = bx * 128;
  const int qw0 = q0 + wid * 32;
  const int qg = qw0 + l31;  // this lane's q-row
  const size_t rowbase = (size_t)b * S_;

  // Q fragments (B-operand of swapped QK^T): lane holds Q[qg][c*16+hi1*8+j]/8
  bf16x8 qf[4];
  {
    const u16* qp = Qb + (rowbase + qg) * D_ + h * 64 + hi1 * 8;
#pragma unroll
    for (int c = 0; c < 4; ++c) {
      bf16x8 v = *(const bf16x8*)(qp + c * 16);
#pragma unroll
      for (int j = 0; j < 8; ++j) v[j] = (short)f2bf(bf2f((u16)v[j]) * 0.125f);
      qf[c] = v;
    }
  }
  float mrun = -3.0e38f, lrun = 0.0f;
  f32x16 o0 = {}, o1 = {};

  // Staging: thread t's data lands at LDS byte t*16 (= wave base + lane*16).
  const u16* kgp =
      Kb + (rowbase + (tid & 31)) * D_ + h * 64 + (tid >> 6) * 16 + ((tid >> 5) & 1) * 8;
  const u16* vgp = VTb +
                   (((size_t)b * H_ + h) * 64 + ((tid >> 6) & 1) * 32 + (tid & 31)) * S_ +
                   (tid >> 7) * 16 + ((tid >> 5) & 1) * 8;
  char* kdst = (char*)Kl + wid * 1024;  // wave-uniform dest
  char* vdst = (char*)Vl + wid * 1024;
  const char* kbase = (const char*)Kl + lane * 16;
  const char* vbase = (const char*)Vl + lane * 16;

  const int kvend = q0 + 128;  // causal bound for this block
  for (int kv0 = 0; kv0 < kvend; kv0 += 32) {
    __syncthreads();  // prior tile's fragment reads complete
    GLD16(kgp + (size_t)kv0 * D_, kdst);
    GLD16(vgp + kv0, vdst);
    __syncthreads();  // staging visible
    if (kv0 > qw0 + 31) continue;  // fully masked for this wave (wave-uniform)

    // QK^T: 4 MFMAs over d-chunks of 16
    f32x16 s = {};
#pragma unroll
    for (int c = 0; c < 4; ++c) s = MFMA32(*(const bf16x8*)(kbase + c * 1024), qf[c], s);

    if (kv0 + 31 > qw0) {  // diagonal tile: causal mask
#pragma unroll
      for (int r = 0; r < 16; ++r) {
        const int kvg = kv0 + (r & 3) + 8 * (r >> 2) + 4 * hi1;
        if (kvg > qg) s[r] = -1.0e30f;
      }
    }
    // online softmax: in-lane reduce + 1 shfl to the partner half-row
    float rm = s[0];
#pragma unroll
    for (int r = 1; r < 16; ++r) rm = fmaxf(rm, s[r]);
    rm = fmaxf(rm, __shfl_xor(rm, 32));
    const float mn = fmaxf(mrun, rm);
    const float fr = __expf(mrun - mn);
    mrun = mn;
    float p[16];
    float rs = 0.0f;
#pragma unroll
    for (int r = 0; r < 16; ++r) {
      p[r] = __expf(s[r] - mn);
      rs += p[r];
    }
    rs += __shfl_xor(rs, 32);
    lrun = lrun * fr + rs;
#pragma unroll
    for (int r = 0; r < 16; ++r) {
      o0[r] *= fr;
      o1[r] *= fr;
    }
    // pack P to bf16 pairs; 4 shfls build both PV B-fragments in-register
    unsigned int pa[4], pb[4];
#pragma unroll
    for (int g = 0; g < 4; ++g) {
      pa[g] = (unsigned)f2bf(p[4 * g]) | ((unsigned)f2bf(p[4 * g + 1]) << 16);
      pb[g] = (unsigned)f2bf(p[4 * g + 2]) | ((unsigned)f2bf(p[4 * g + 3]) << 16);
    }
    const unsigned sa = __shfl_xor(hi1 ? pa[0] : pa[1], 32);
    const unsigned sb = __shfl_xor(hi1 ? pb[0] : pb[1], 32);
    const unsigned sc = __shfl_xor(hi1 ? pa[2] : pa[3], 32);
    const unsigned sd = __shfl_xor(hi1 ? pb[2] : pb[3], 32);
    const uint4 w0 = hi1 ? make_uint4(sa, sb, pa[1], pb[1]) : make_uint4(pa[0], pb[0], sa, sb);
    const uint4 w1 = hi1 ? make_uint4(sc, sd, pa[3], pb[3]) : make_uint4(pa[2], pb[2], sc, sd);
    bf16x8 pf0, pf1;
    __builtin_memcpy(&pf0, &w0, 16);
    __builtin_memcpy(&pf1, &w1, 16);
    // PV: O^T += V^T_chunk . P^T  (4 MFMAs: kvchunk x dblk)
    o0 = MFMA32(*(const bf16x8*)(vbase + 0 * 1024), pf0, o0);
    o1 = MFMA32(*(const bf16x8*)(vbase + 1 * 1024), pf0, o1);
    o0 = MFMA32(*(const bf16x8*)(vbase + 2 * 1024), pf1, o0);
    o1 = MFMA32(*(const bf16x8*)(vbase + 3 * 1024), pf1, o1);
  }
  // epilogue: lane owns q; rows are d-offsets (r&3)+8*(r>>2)+4*hi1
  const float inv = 1.0f / lrun;
  u16* op = att + (rowbase + qg) * D_ + h * 64;
#pragma unroll
  for (int g = 0; g < 4; ++g) {
    u16x4 v0, v1;
#pragma unroll
    for (int j = 0; j < 4; ++j) {
      v0[j] = f2bf(o0[4 * g + j] * inv);
      v1[j] = f2bf(o1[4 * g + j] * inv);
    }
    *(u16x4*)(op + 8 * g + 4 * hi1) = v0;
    *(u16x4*)(op + 32 + 8 * g + 4 * hi1) = v1;
  }
}

// ---------------------------------------------------------------------------
extern "C" void kernel_launch(void* const* d_in, const int* in_sizes, int n_in, void* d_out,
                              int out_size, void* d_ws, size_t ws_size, hipStream_t stream) {
  // Assign inputs by unique element count (robust to input ordering).
  const float *x = nullptr, *Wqkv = nullptr, *bqkv = nullptr, *Wo = nullptr, *bo = nullptr;
  for (int i = 0; i < n_in; ++i) {
    switch (in_sizes[i]) {
      case 16384 * 768:  x = (const float*)d_in[i]; break;     // [16,1024,768]
      case 768 * 2304:   Wqkv = (const float*)d_in[i]; break;  // [768,2304]
      case 2304:         bqkv = (const float*)d_in[i]; break;  // [2304]
      case 768 * 768:    Wo = (const float*)d_in[i]; break;    // [768,768]
      case 768:          bo = (const float*)d_in[i]; break;    // [768]
    }
  }
  float* out = (float*)d_out;  // [16,1024,768] FLOAT32

  char* ws = (char*)d_ws;
  u16* WqkvT = (u16*)(ws);              // 2304*768*2  = 3,538,944
  u16* WoT = (u16*)(ws + 3538944);      // 768*768*2   = 1,179,648
  u16* Qb = (u16*)(ws + 4718592);       // 16384*768*2 = 25,165,824
  u16* Kb = (u16*)(ws + 29884416);      // 25,165,824
  u16* VT = (u16*)(ws + 55050240);      // 25,165,824 -> ws total 80,216,064 B
  u16* xb = (u16*)d_out;  // bf16 x staged in d_out; dead before final GEMM
  u16* att = Qb;          // alias: attn block reads its own Q region first

  prep<<<8448, 256, 0, stream>>>(x, xb, Wqkv, WqkvT, Wo, WoT);
  gemm_bt<0><<<2304, 256, 0, stream>>>(xb, WqkvT, bqkv, Qb, Kb, VT, nullptr,
                                       16384, 2304, 768, 18);
  attn_fwd2<<<dim3(8, H_, B_), 256, 0, stream>>>(Qb, Kb, VT, att);
  gemm_bt<1><<<768, 256, 0, stream>>>(att, WoT, bo, nullptr, nullptr, nullptr, out,
                                      16384, 768, 768, 6);
}

// Round 16
// 222.099 us; speedup vs baseline: 2.7532x; 1.0792x over previous
//
#include <hip/hip_runtime.h>
#include <stdint.h>

typedef unsigned short u16;
typedef __attribute__((ext_vector_type(8))) short bf16x8;
typedef __attribute__((ext_vector_type(8))) u16 u16x8;
typedef __attribute__((ext_vector_type(4))) u16 u16x4;
typedef __attribute__((ext_vector_type(4))) float f32x4;
typedef __attribute__((ext_vector_type(16))) float f32x16;

#define B_ 16
#define S_ 1024
#define D_ 768
#define H_ 12

__device__ __forceinline__ float bf2f(u16 u) {
  unsigned int x = ((unsigned int)u) << 16;
  float f;
  __builtin_memcpy(&f, &x, 4);
  return f;
}
__device__ __forceinline__ u16 f2bf(float f) {
  unsigned int x;
  __builtin_memcpy(&x, &f, 4);
  x += 0x7fffu + ((x >> 16) & 1u);
  return (u16)(x >> 16);
}
__device__ __forceinline__ unsigned cvt_pk_bf16(float lo, float hi) {
  unsigned r;
  asm("v_cvt_pk_bf16_f32 %0, %1, %2" : "=v"(r) : "v"(lo), "v"(hi));
  return r;  // lo -> bits[15:0], hi -> bits[31:16]
}

#define MFMA16(a, b, c) __builtin_amdgcn_mfma_f32_16x16x32_bf16((a), (b), (c), 0, 0, 0)
#define MFMA32(a, b, c) __builtin_amdgcn_mfma_f32_32x32x16_bf16((a), (b), (c), 0, 0, 0)

#define GLD16(g, l)                                              \
  __builtin_amdgcn_global_load_lds(                              \
      (const __attribute__((address_space(1))) void*)(g),        \
      (__attribute__((address_space(3))) void*)(l), 16, 0, 0)

// ---------------------------------------------------------------------------
// Fused prologue: f32->bf16 convert of x + two transpose-convert weights.
// ---------------------------------------------------------------------------
__global__ __launch_bounds__(256) void prep(const float* __restrict__ x,
                                            u16* __restrict__ xb,
                                            const float* __restrict__ Wqkv,
                                            u16* __restrict__ WqkvT,
                                            const float* __restrict__ Wo,
                                            u16* __restrict__ WoT) {
  __shared__ u16 tt[32][33];
  const int gx = blockIdx.x;
  const int tid = threadIdx.x;
  if (gx < 6144) {  // cvt x: 16384*768/8 = 1,572,864 vec8 elems, exact
    const int i = gx * 256 + tid;
    const float4 a = *(const float4*)(x + (size_t)i * 8);
    const float4 b = *(const float4*)(x + (size_t)i * 8 + 4);
    u16x8 o;
    o[0] = f2bf(a.x); o[1] = f2bf(a.y); o[2] = f2bf(a.z); o[3] = f2bf(a.w);
    o[4] = f2bf(b.x); o[5] = f2bf(b.y); o[6] = f2bf(b.z); o[7] = f2bf(b.w);
    *(u16x8*)(xb + (size_t)i * 8) = o;
  } else if (gx < 6144 + 1728) {  // Wqkv [768,2304] -> WqkvT [2304,768]
    const int t = gx - 6144;
    const int n0 = (t % 72) * 32, k0 = (t / 72) * 32;
    const int tx = tid & 31, ty = tid >> 5;
#pragma unroll
    for (int i = 0; i < 32; i += 8)
      tt[ty + i][tx] = f2bf(Wqkv[(size_t)(k0 + ty + i) * 2304 + n0 + tx]);
    __syncthreads();
#pragma unroll
    for (int i = 0; i < 32; i += 8)
      WqkvT[(size_t)(n0 + ty + i) * 768 + k0 + tx] = tt[tx][ty + i];
  } else {  // Wo [768,768] -> WoT [768,768]
    const int t = gx - 7872;
    const int n0 = (t % 24) * 32, k0 = (t / 24) * 32;
    const int tx = tid & 31, ty = tid >> 5;
#pragma unroll
    for (int i = 0; i < 32; i += 8)
      tt[ty + i][tx] = f2bf(Wo[(size_t)(k0 + ty + i) * 768 + n0 + tx]);
    __syncthreads();
#pragma unroll
    for (int i = 0; i < 32; i += 8)
      WoT[(size_t)(n0 + ty + i) * 768 + k0 + tx] = tt[tx][ty + i];
  }
}

// ---------------------------------------------------------------------------
// 128x128x64 MFMA GEMM + XCD-stripe schedule (r15, unchanged - the proven
// fastest GEMM: XOR-swizzled LDS, dist-1 dbuf, per-XCD B-residency).
// ---------------------------------------------------------------------------
template <int MODE>
__global__ __launch_bounds__(256, 2) void gemm_bt(const u16* __restrict__ A,
                                                  const u16* __restrict__ Bt,
                                                  const float* __restrict__ bias,
                                                  u16* __restrict__ O0, u16* __restrict__ O1,
                                                  u16* __restrict__ O2, float* __restrict__ Of,
                                                  int M, int N, int K, int NBT) {
  __shared__ u16 Al[2 * 128 * 64];  // 2 bufs x 16 KB
  __shared__ u16 Bl[2 * 128 * 64];
  const int tid = threadIdx.x;
  const int wid = tid >> 6, lane = tid & 63;
  const int lo = lane & 15, hi = lane >> 4;
  const int wr = wid >> 1, wc = wid & 1;
  const int bid = blockIdx.x;
  const int xcd = bid & 7, idx = bid >> 3;
  const int mb = xcd * 16 + idx / NBT;
  const int nb = idx % NBT;
  const int m0 = mb * 128, n0 = nb * 128;
  const int T = K >> 6;  // 12

  const int sr = lane >> 3;
  const int kk = ((lane & 7) ^ sr) * 8;  // pre-swizzled k element offset
  const u16* const asrc = A + (size_t)(m0 + wid * 8 + sr) * K + kk;
  const u16* const bsrc = Bt + (size_t)(n0 + wid * 8 + sr) * K + kk;

#define STAGE(kt, buf)                                                          \
  do {                                                                          \
    const size_t _k = (size_t)(kt) * 64;                                        \
    GLD16(asrc + _k, (char*)Al + (buf) * 16384 + (wid) * 1024);                 \
    GLD16(asrc + (size_t)32 * K + _k, (char*)Al + (buf) * 16384 + (wid + 4) * 1024);  \
    GLD16(asrc + (size_t)64 * K + _k, (char*)Al + (buf) * 16384 + (wid + 8) * 1024);  \
    GLD16(asrc + (size_t)96 * K + _k, (char*)Al + (buf) * 16384 + (wid + 12) * 1024); \
    GLD16(bsrc + _k, (char*)Bl + (buf) * 16384 + (wid) * 1024);                 \
    GLD16(bsrc + (size_t)32 * K + _k, (char*)Bl + (buf) * 16384 + (wid + 4) * 1024);  \
    GLD16(bsrc + (size_t)64 * K + _k, (char*)Bl + (buf) * 16384 + (wid + 8) * 1024);  \
    GLD16(bsrc + (size_t)96 * K + _k, (char*)Bl + (buf) * 16384 + (wid + 12) * 1024); \
  } while (0)

  f32x4 acc[4][4] = {};

  STAGE(0, 0);
  asm volatile("s_waitcnt vmcnt(0)" ::: "memory");
  __builtin_amdgcn_s_barrier();

  for (int t = 0; t < T; ++t) {
    if (t + 1 < T) STAGE(t + 1, (t + 1) & 1);
    const int cb = (t & 1) * 16384;
    const int swz = (lo & 7) << 4;
    bf16x8 af[4][2], bfv[4][2];
#pragma unroll
    for (int i = 0; i < 4; ++i)
#pragma unroll
      for (int s = 0; s < 2; ++s)
        af[i][s] = *(const bf16x8*)((const char*)Al + cb + (wr * 64 + i * 16 + lo) * 128 +
                                    ((s * 64 + hi * 16) ^ swz));
#pragma unroll
    for (int j = 0; j < 4; ++j)
#pragma unroll
      for (int s = 0; s < 2; ++s)
        bfv[j][s] = *(const bf16x8*)((const char*)Bl + cb + (wc * 64 + j * 16 + lo) * 128 +
                                     ((s * 64 + hi * 16) ^ swz));
    __builtin_amdgcn_s_setprio(1);
#pragma unroll
    for (int i = 0; i < 4; ++i)
#pragma unroll
      for (int j = 0; j < 4; ++j) {
        acc[i][j] = MFMA16(af[i][0], bfv[j][0], acc[i][j]);
        acc[i][j] = MFMA16(af[i][1], bfv[j][1], acc[i][j]);
      }
    __builtin_amdgcn_s_setprio(0);
    if (t + 1 < T) asm volatile("s_waitcnt vmcnt(0)" ::: "memory");
    __builtin_amdgcn_s_barrier();
  }
#undef STAGE
  if (MODE == 0 && n0 >= 2 * D_) {
#pragma unroll
    for (int g = 0; g < 4; ++g) {
      const int n = n0 + wc * 64 + g * 16 + lo;
      const float bv = bias[n];
      const int np = n - 2 * D_;
#pragma unroll
      for (int f = 0; f < 4; ++f) {
        const int m = m0 + wr * 64 + f * 16 + hi * 4;
        u16x4 q;
#pragma unroll
        for (int r = 0; r < 4; ++r) q[r] = f2bf(acc[f][g][r] + bv);
        *(u16x4*)&O2[(((size_t)(m >> 10) * H_ + (np >> 6)) * 64 + (np & 63)) * S_ +
                     (m & 1023)] = q;
      }
    }
  } else {
#pragma unroll
    for (int g = 0; g < 4; ++g) {
      const int n = n0 + wc * 64 + g * 16 + lo;
      const float bv = bias[n];
#pragma unroll
      for (int f = 0; f < 4; ++f) {
#pragma unroll
        for (int r = 0; r < 4; ++r) {
          const int m = m0 + wr * 64 + f * 16 + hi * 4 + r;
          const float fv = acc[f][g][r] + bv;
          if (MODE == 0) {
            const u16 o = f2bf(fv);
            if (n0 < D_) {
              O0[(size_t)m * D_ + n] = o;
            } else {
              O1[(size_t)m * D_ + (n - D_)] = o;
            }
          } else {
            Of[(size_t)m * N + n] = fv;
          }
        }
      }
    }
  }
}

// ---------------------------------------------------------------------------
// Flash attention v3: swapped-operand 32x32 MFMA + in-register softmax +
//   (1) v_cvt_pk_bf16_f32 P-packing (T12: ~72 VALU -> 8 per tile),
//   (2) defer-max rescale THR=8 (T13: skip 32-mult O-rescale on most tiles),
//   (3) double-buffered K/V staging, ONE barrier/tile, stage(t+1) issued
//       before compute(t) so the drain lands after ~300 cyc of work.
// Heavy causal blocks (bx=7) dispatch first (tail balance).
// ---------------------------------------------------------------------------
__global__ __launch_bounds__(256) void attn_fwd3(const u16* __restrict__ Qb,
                                                 const u16* __restrict__ Kb,
                                                 const u16* __restrict__ VTb,
                                                 u16* __restrict__ att) {
  __shared__ u16 Kl[2 * 2048];  // 2 bufs x 4 KB
  __shared__ u16 Vl[2 * 2048];
  const int tid = threadIdx.x;
  const int lane = tid & 63, wid = tid >> 6;
  const int l31 = lane & 31, hi1 = lane >> 5;
  const int L = blockIdx.x + 8 * (blockIdx.y + 12 * blockIdx.z);
  const int bx = 7 - ((L >> 3) & 7);  // heavy (large-bx) blocks first
  const int P = (L & 7) + 8 * (L >> 6);
  const int h = P % 12, b = P / 12;
  const int q0 = bx * 128;
  const int qw0 = q0 + wid * 32;
  const int qg = qw0 + l31;
  const size_t rowbase = (size_t)b * S_;

  // Q fragments (B-operand of swapped QK^T), pre-scaled by 0.125
  bf16x8 qf[4];
  {
    const u16* qp = Qb + (rowbase + qg) * D_ + h * 64 + hi1 * 8;
#pragma unroll
    for (int c = 0; c < 4; ++c) {
      bf16x8 v = *(const bf16x8*)(qp + c * 16);
#pragma unroll
      for (int j = 0; j < 8; ++j) v[j] = (short)f2bf(bf2f((u16)v[j]) * 0.125f);
      qf[c] = v;
    }
  }
  float mrun = -3.0e38f, lrun = 0.0f;
  f32x16 o0 = {}, o1 = {};

  const u16* kgp =
      Kb + (rowbase + (tid & 31)) * D_ + h * 64 + (tid >> 6) * 16 + ((tid >> 5) & 1) * 8;
  const u16* vgp = VTb +
                   (((size_t)b * H_ + h) * 64 + ((tid >> 6) & 1) * 32 + (tid & 31)) * S_ +
                   (tid >> 7) * 16 + ((tid >> 5) & 1) * 8;
  char* const kdst = (char*)Kl + wid * 1024;  // + buf*4096 (wave-uniform)
  char* const vdst = (char*)Vl + wid * 1024;
  const char* const kbase = (const char*)Kl + lane * 16;  // + buf*4096 + c*1024
  const char* const vbase = (const char*)Vl + lane * 16;

  const int T = (q0 + 128) >> 5;  // causal tile count for this block

  // prologue: stage tile 0 into buf 0
  GLD16(kgp, kdst);
  GLD16(vgp, vdst);
  asm volatile("s_waitcnt vmcnt(0)" ::: "memory");
  __builtin_amdgcn_s_barrier();

  for (int t = 0; t < T; ++t) {
    const int kv0 = t * 32;
    if (t + 1 < T) {  // issue next tile's loads BEFORE compute (dist-1)
      const int nb = ((t + 1) & 1) * 4096;
      GLD16(kgp + (size_t)(t + 1) * 32 * D_, kdst + nb);
      GLD16(vgp + (t + 1) * 32, vdst + nb);
    }
    if (kv0 <= qw0 + 31) {  // wave-uniform: unmasked tile for this wave
      const int cb = (t & 1) * 4096;
      // QK^T: 4 MFMAs over d-chunks of 16
      f32x16 s = {};
#pragma unroll
      for (int c = 0; c < 4; ++c)
        s = MFMA32(*(const bf16x8*)(kbase + cb + c * 1024), qf[c], s);

      if (kv0 + 31 > qw0) {  // diagonal tile: causal mask
#pragma unroll
        for (int r = 0; r < 16; ++r) {
          const int kvg = kv0 + (r & 3) + 8 * (r >> 2) + 4 * hi1;
          if (kvg > qg) s[r] = -1.0e30f;
        }
      }
      // row max (in-lane tree + cross-half shfl)
      float rm = s[0];
#pragma unroll
      for (int r = 1; r < 16; ++r) rm = fmaxf(rm, s[r]);
      rm = fmaxf(rm, __shfl_xor(rm, 32));
      // defer-max (T13): rescale only when the max grew past THR=8
      if (!__all(rm - mrun <= 8.0f)) {
        const float mn = fmaxf(mrun, rm);
        const float fr = __expf(mrun - mn);
        mrun = mn;
        lrun *= fr;
#pragma unroll
        for (int r = 0; r < 16; ++r) {
          o0[r] *= fr;
          o1[r] *= fr;
        }
      }
      float p[16];
      float rs = 0.0f;
#pragma unroll
      for (int r = 0; r < 16; ++r) {
        p[r] = __expf(s[r] - mrun);
        rs += p[r];
      }
      rs += __shfl_xor(rs, 32);
      lrun += rs;
      // pack P via v_cvt_pk_bf16_f32 (T12); 4 shfls build both PV B-frags
      unsigned int pa[4], pb[4];
#pragma unroll
      for (int g = 0; g < 4; ++g) {
        pa[g] = cvt_pk_bf16(p[4 * g], p[4 * g + 1]);
        pb[g] = cvt_pk_bf16(p[4 * g + 2], p[4 * g + 3]);
      }
      const unsigned sa = __shfl_xor(hi1 ? pa[0] : pa[1], 32);
      const unsigned sb = __shfl_xor(hi1 ? pb[0] : pb[1], 32);
      const unsigned sc = __shfl_xor(hi1 ? pa[2] : pa[3], 32);
      const unsigned sd = __shfl_xor(hi1 ? pb[2] : pb[3], 32);
      const uint4 w0 =
          hi1 ? make_uint4(sa, sb, pa[1], pb[1]) : make_uint4(pa[0], pb[0], sa, sb);
      const uint4 w1 =
          hi1 ? make_uint4(sc, sd, pa[3], pb[3]) : make_uint4(pa[2], pb[2], sc, sd);
      bf16x8 pf0, pf1;
      __builtin_memcpy(&pf0, &w0, 16);
      __builtin_memcpy(&pf1, &w1, 16);
      // PV: O^T += V^T_chunk . P^T
      o0 = MFMA32(*(const bf16x8*)(vbase + cb + 0 * 1024), pf0, o0);
      o1 = MFMA32(*(const bf16x8*)(vbase + cb + 1 * 1024), pf0, o1);
      o0 = MFMA32(*(const bf16x8*)(vbase + cb + 2 * 1024), pf1, o0);
      o1 = MFMA32(*(const bf16x8*)(vbase + cb + 3 * 1024), pf1, o1);
    }
    // drain next tile's loads (flew under compute) + all waves done with cur
    asm volatile("s_waitcnt vmcnt(0)" ::: "memory");
    __builtin_amdgcn_s_barrier();
  }
  // epilogue: lane owns q; rows are d-offsets (r&3)+8*(r>>2)+4*hi1
  const float inv = 1.0f / lrun;
  u16* op = att + (rowbase + qg) * D_ + h * 64;
#pragma unroll
  for (int g = 0; g < 4; ++g) {
    u16x4 v0, v1;
#pragma unroll
    for (int j = 0; j < 4; ++j) {
      v0[j] = f2bf(o0[4 * g + j] * inv);
      v1[j] = f2bf(o1[4 * g + j] * inv);
    }
    *(u16x4*)(op + 8 * g + 4 * hi1) = v0;
    *(u16x4*)(op + 32 + 8 * g + 4 * hi1) = v1;
  }
}

// ---------------------------------------------------------------------------
extern "C" void kernel_launch(void* const* d_in, const int* in_sizes, int n_in, void* d_out,
                              int out_size, void* d_ws, size_t ws_size, hipStream_t stream) {
  const float *x = nullptr, *Wqkv = nullptr, *bqkv = nullptr, *Wo = nullptr, *bo = nullptr;
  for (int i = 0; i < n_in; ++i) {
    switch (in_sizes[i]) {
      case 16384 * 768:  x = (const float*)d_in[i]; break;
      case 768 * 2304:   Wqkv = (const float*)d_in[i]; break;
      case 2304:         bqkv = (const float*)d_in[i]; break;
      case 768 * 768:    Wo = (const float*)d_in[i]; break;
      case 768:          bo = (const float*)d_in[i]; break;
    }
  }
  float* out = (float*)d_out;  // [16,1024,768] FLOAT32

  char* ws = (char*)d_ws;
  u16* WqkvT = (u16*)(ws);              // 2304*768*2  = 3,538,944
  u16* WoT = (u16*)(ws + 3538944);      // 768*768*2   = 1,179,648
  u16* Qb = (u16*)(ws + 4718592);       // 16384*768*2 = 25,165,824
  u16* Kb = (u16*)(ws + 29884416);      // 25,165,824
  u16* VT = (u16*)(ws + 55050240);      // 25,165,824 -> ws total 80,216,064 B
  u16* xb = (u16*)d_out;  // bf16 x staged in d_out; dead before final GEMM
  u16* att = Qb;          // alias: attn block reads its own Q region first

  prep<<<8448, 256, 0, stream>>>(x, xb, Wqkv, WqkvT, Wo, WoT);
  gemm_bt<0><<<2304, 256, 0, stream>>>(xb, WqkvT, bqkv, Qb, Kb, VT, nullptr,
                                       16384, 2304, 768, 18);
  attn_fwd3<<<dim3(8, H_, B_), 256, 0, stream>>>(Qb, Kb, VT, att);
  gemm_bt<1><<<768, 256, 0, stream>>>(att, WoT, bo, nullptr, nullptr, nullptr, out,
                                      16384, 768, 768, 6);
}